// Round 6
// baseline (1669.497 us; speedup 1.0000x reference)
//
#include <hip/hip_runtime.h>
#include <stdint.h>

#define M_TOK 2048
#define HID   1024
#define NEXP  64
#define TOPK  6
#define TOTSLOT (M_TOK*TOPK)   // 12288

typedef unsigned short u16;
typedef __attribute__((ext_vector_type(4))) u16   u16x4;
typedef __attribute__((ext_vector_type(8))) u16   u16x8;
typedef __attribute__((ext_vector_type(4))) float f32x4;
typedef __attribute__((ext_vector_type(8))) short bf16x8;

__device__ __forceinline__ u16 f2b(float f) {
    union { float f; uint32_t u; } v; v.f = f;
    uint32_t r = v.u + 0x7FFFu + ((v.u >> 16) & 1u);
    return (u16)(r >> 16);
}
__device__ __forceinline__ float b2f(u16 b) {
    union { uint32_t u; float f; } v; v.u = ((uint32_t)b) << 16; return v.f;
}

// ---------------- x fp32 -> bf16 ----------------
__global__ __launch_bounds__(256) void convert_x_kernel(const float* __restrict__ x,
                                                        u16* __restrict__ xb) {
    int i = (blockIdx.x * 256 + threadIdx.x) * 4;
    float4 v = *reinterpret_cast<const float4*>(x + i);
    u16x4 o; o[0] = f2b(v.x); o[1] = f2b(v.y); o[2] = f2b(v.z); o[3] = f2b(v.w);
    *reinterpret_cast<u16x4*>(xb + i) = o;
}

// ---------------- gw transpose: gwT[k][e] so router lanes read coalesced ----------------
__global__ __launch_bounds__(256) void transpose_gw_kernel(const float* __restrict__ gw,
                                                           float* __restrict__ gwT) {
    int i = blockIdx.x * 256 + threadIdx.x;   // 65536 elements
    int e = i >> 10, k = i & 1023;
    gwT[k * NEXP + e] = gw[i];
}

// ---------------- router: fp64 logits (coalesced gwT), grouped topk ----------------
__global__ __launch_bounds__(64) void router_kernel(
    const float* __restrict__ x, const float* __restrict__ gwT,
    int* __restrict__ topk_id, float* __restrict__ topk_w, int* __restrict__ counts)
{
    int t = blockIdx.x, lane = threadIdx.x;
    __shared__ float xr[HID];
    for (int k = lane; k < HID; k += 64) xr[k] = x[(size_t)t * HID + k];
    __syncthreads();
    double s0 = 0.0, s1 = 0.0, s2 = 0.0, s3 = 0.0;
    for (int k = 0; k < HID; k += 4) {
        s0 += (double)xr[k]   * (double)gwT[(k)   * NEXP + lane];
        s1 += (double)xr[k+1] * (double)gwT[(k+1) * NEXP + lane];
        s2 += (double)xr[k+2] * (double)gwT[(k+2) * NEXP + lane];
        s3 += (double)xr[k+3] * (double)gwT[(k+3) * NEXP + lane];
    }
    double s = (s0 + s1) + (s2 + s3);
    __shared__ double lg[NEXP];
    __shared__ float  pr[NEXP];
    float sf = (float)s;
    float mx = sf;
    for (int o = 32; o; o >>= 1) mx = fmaxf(mx, __shfl_xor(mx, o));
    float ev = __expf(sf - mx);
    float sum = ev;
    for (int o = 32; o; o >>= 1) sum += __shfl_xor(sum, o);
    lg[lane] = s; pr[lane] = ev / sum;
    __syncthreads();
    if (lane == 0) {
        double gs[8];
        #pragma unroll
        for (int g = 0; g < 8; ++g) {
            double m = lg[g*8];
            #pragma unroll
            for (int i = 1; i < 8; ++i) m = fmax(m, lg[g*8+i]);
            gs[g] = m;
        }
        unsigned gsel = 0;
        for (int r = 0; r < 3; ++r) {
            int bi = 0; double bv = -1e300;
            for (int g = 0; g < 8; ++g)
                if (!((gsel>>g)&1u) && gs[g] > bv) { bv = gs[g]; bi = g; }
            gsel |= 1u << bi;
        }
        unsigned long long taken = 0;
        for (int r = 0; r < TOPK; ++r) {
            int bi = 0; double bv = -1e300;
            for (int e = 0; e < NEXP; ++e) {
                if (!((gsel >> (e>>3)) & 1u)) continue;
                if ((taken >> e) & 1ull) continue;
                if (lg[e] > bv) { bv = lg[e]; bi = e; }
            }
            taken |= 1ull << bi;
            topk_id[t*TOPK + r] = bi;
            topk_w[t*TOPK + r] = pr[bi];
            atomicAdd(&counts[bi], 1);
        }
    }
}

__global__ void scan_kernel(const int* __restrict__ counts, int* __restrict__ offs,
                            int* __restrict__ cursor) {
    if (threadIdx.x == 0) {
        int acc = 0;
        for (int e = 0; e < NEXP; ++e) { offs[e] = acc; cursor[e] = acc; acc += counts[e]; }
        offs[NEXP] = acc;
    }
}

__global__ __launch_bounds__(256) void fill_kernel(
    const int* __restrict__ topk_id, const float* __restrict__ topk_w,
    int* __restrict__ cursor, int* __restrict__ stok, float* __restrict__ sw,
    int* __restrict__ spos)
{
    int idx = blockIdx.x*256 + threadIdx.x;
    if (idx >= TOTSLOT) return;
    int e = topk_id[idx];
    int pos = atomicAdd(&cursor[e], 1);
    stok[pos] = idx / TOPK;
    sw[pos] = topk_w[idx];
    spos[idx] = pos;
}

// ---------------- unified MFMA GEMM: A in registers, B LDS double-buffered ----------------
// KIND 0: routed gate/up  BM=256 BN=128  A=x_bf16[tok] K=1024, B=w1[e] -> h (bf16)
// KIND 1: shared gate/up  BM=256 BN=128  A=x_bf16     K=1024, B=sgu  -> hs (bf16)
// KIND 2: routed down     BM=256 BN=128  A=h          K=1024, B=w2[e]-> y  (bf16)
// KIND 3: shared down     BM=128 BN=64   A=hs         K=2048, B=sdn  -> Out (f32)
// Fat waves: wave owns 32 M-rows (acc[2][NF]); 2 blocks/CU co-resident (decoupled barriers).
template<int KIND>
__global__ __launch_bounds__((KIND==3) ? 256 : 512, 4) void gemm_kernel(
    const u16* __restrict__ A, const float* __restrict__ Bw,
    u16* __restrict__ Hout, float* __restrict__ Out,
    const int* __restrict__ offs, const int* __restrict__ stok,
    const float* __restrict__ sw)
{
    constexpr bool G1     = (KIND == 0 || KIND == 1);
    constexpr bool ROUTED = (KIND == 0 || KIND == 2);
    constexpr int  BM     = (KIND == 3) ? 128 : 256;
    constexpr int  BN     = (KIND == 3) ? 64 : 128;
    constexpr int  NF     = BN / 16;
    constexpr int  KD     = (KIND == 3) ? 2048 : 1024;
    constexpr int  KITER  = KD / 64;
    constexpr int  NPAIR  = (KIND == 0) ? 1024 : 2048;  // up-row offset / Hout stride
    constexpr int  T      = BM * 2;       // waves = BM/32
    constexpr int  TPR    = T / BN;       // B-stage threads per row (4)
    constexpr int  CPT    = 64 / TPR;     // B fp32 cols per thread (16)
    constexpr int  BREG   = CPT / 4;      // 4

    __shared__ u16 Bs[2][BN*64];          // 32 KB (16 KB for KIND 3)
    __shared__ int   tkl[ROUTED ? BM : 1];
    __shared__ float swl[(KIND == 0) ? BM : 1];

    const int tid  = threadIdx.x;
    const int lane = tid & 63;
    const int wv   = tid >> 6;            // BM/32 waves, each owns 32 M-rows x BN

    const int e = ROUTED ? blockIdx.z : 0;
    int off = 0, cnt = M_TOK;
    if (ROUTED) { off = offs[e]; cnt = offs[e+1] - off; }
    const int m0 = blockIdx.y * BM;
    if (m0 >= cnt) return;
    const int nblk = blockIdx.x;

    if (ROUTED && tid < BM) {
        int gr = m0 + tid;
        if (KIND == 0) {
            tkl[tid] = (gr < cnt) ? stok[off + gr] : 0;
            swl[tid] = (gr < cnt) ? sw[off + gr] : 0.f;
        } else {
            int r = off + gr; if (r > TOTSLOT-1) r = TOTSLOT-1;
            tkl[tid] = r;
        }
    }
    __syncthreads();

    // Per-lane A base pointers (A fragments load straight to VGPRs; data is L2/L3-hot)
    const u16* ap[2];
    #pragma unroll
    for (int mf = 0; mf < 2; ++mf) {
        int r = wv*32 + mf*16 + (lane & 15);
        int arow = ROUTED ? tkl[r] : (m0 + r);
        ap[mf] = A + (size_t)arow * KD + (lane >> 4) * 8;
    }

    const float* Be = Bw;
    if (KIND == 0) Be += (size_t)e * (size_t)(2*1024*1024);
    if (KIND == 2) Be += (size_t)e * (size_t)(1024*1024);
    const int rb = tid / TPR;             // B tile row 0..BN-1
    const int q  = tid % TPR;
    int brow;
    if (G1) brow = (rb < 64) ? (nblk*64 + rb) : (NPAIR + nblk*64 + (rb - 64));
    else    brow = nblk*BN + rb;
    const float* bsrc = Be + (size_t)brow * KD + q*CPT;

    float4 br[BREG];
    bf16x8 afE[2][2], afO[2][2];          // A fragments, even/odd K-steps

    auto loadB = [&](int k0) {
        #pragma unroll
        for (int j = 0; j < BREG; ++j)
            br[j] = *reinterpret_cast<const float4*>(bsrc + k0 + j*4);
    };
    auto storeB = [&](int buf) {
        char* bd = (char*)&Bs[buf][0] + rb*128;
        #pragma unroll
        for (int jj = 0; jj < CPT/8; ++jj) {
            u16x8 w;
            w[0] = f2b(br[2*jj].x);   w[1] = f2b(br[2*jj].y);
            w[2] = f2b(br[2*jj].z);   w[3] = f2b(br[2*jj].w);
            w[4] = f2b(br[2*jj+1].x); w[5] = f2b(br[2*jj+1].y);
            w[6] = f2b(br[2*jj+1].z); w[7] = f2b(br[2*jj+1].w);
            int cb = q*(CPT*2) + jj*16;
            *reinterpret_cast<u16x8*>(bd + (cb ^ ((rb & 7) << 4))) = w;
        }
    };
    auto loadA = [&](bf16x8 (&af)[2][2], int k0) {
        #pragma unroll
        for (int mf = 0; mf < 2; ++mf)
            #pragma unroll
            for (int kk = 0; kk < 2; ++kk)
                af[mf][kk] = *reinterpret_cast<const bf16x8*>(ap[mf] + k0 + kk*32);
    };

    f32x4 acc[2][NF];
    #pragma unroll
    for (int mf = 0; mf < 2; ++mf)
        #pragma unroll
        for (int nf = 0; nf < NF; ++nf)
            acc[mf][nf] = (f32x4){0.f, 0.f, 0.f, 0.f};

    auto mfma_phase = [&](bf16x8 (&af)[2][2], int bi) {
        #pragma unroll
        for (int kk = 0; kk < 2; ++kk) {
            const int slot = kk*4 + (lane >> 4);
            bf16x8 bfr[NF];
            #pragma unroll
            for (int nf = 0; nf < NF; ++nf) {
                int r = nf*16 + (lane & 15);
                bfr[nf] = *reinterpret_cast<const bf16x8*>(
                    (const char*)&Bs[bi][0] + r*128 + ((slot ^ (r & 7)) << 4));
            }
            #pragma unroll
            for (int mf = 0; mf < 2; ++mf)
                #pragma unroll
                for (int nf = 0; nf < NF; ++nf)
                    acc[mf][nf] = __builtin_amdgcn_mfma_f32_16x16x32_bf16(af[mf][kk], bfr[nf], acc[mf][nf], 0, 0, 0);
        }
    };

    auto step = [&](int kt, bf16x8 (&af)[2][2]) {
        if (kt + 1 < KITER) loadB((kt + 1) * 64);   // B for next tile -> regs
        mfma_phase(af, kt & 1);                      // compute current tile
        if (kt + 2 < KITER) loadA(af, (kt + 2) * 64);// refill this A set, 2 ahead
        if (kt + 1 < KITER) storeB((kt + 1) & 1);    // convert+write next B tile
        __syncthreads();                             // one barrier per K-step
    };

    // prologue
    loadB(0);
    loadA(afE, 0);
    loadA(afO, 64);
    storeB(0);
    __syncthreads();

    for (int kt2 = 0; kt2 < KITER; kt2 += 2) {
        step(kt2,     afE);
        step(kt2 + 1, afO);
    }

    if constexpr (G1) {
        const int colbase = nblk*64 + (lane & 15);
        #pragma unroll
        for (int mf = 0; mf < 2; ++mf) {
            #pragma unroll
            for (int j = 0; j < 4; ++j) {
                int r = wv*32 + mf*16 + (lane >> 4)*4 + j;
                if (ROUTED && (m0 + r) >= cnt) continue;
                float wgt = (KIND == 0) ? swl[r] : 1.0f;
                size_t orow = (size_t)(ROUTED ? (off + m0 + r) : (m0 + r));
                #pragma unroll
                for (int nf = 0; nf < 4; ++nf) {
                    float g = acc[mf][nf][j];
                    float u = acc[mf][nf+4][j];
                    float hv = (g / (1.f + __expf(-g))) * u * wgt;
                    Hout[orow * NPAIR + colbase + nf*16] = f2b(hv);
                }
            }
        }
    } else {
        const int colbase = nblk*BN + (lane & 15);
        #pragma unroll
        for (int mf = 0; mf < 2; ++mf) {
            #pragma unroll
            for (int j = 0; j < 4; ++j) {
                int r = wv*32 + mf*16 + (lane >> 4)*4 + j;
                if (ROUTED && (m0 + r) >= cnt) continue;
                #pragma unroll
                for (int nf = 0; nf < NF; ++nf) {
                    float v = acc[mf][nf][j];
                    if (KIND == 2) Hout[(size_t)(off + m0 + r) * HID + colbase + nf*16] = f2b(v);
                    else           Out[(size_t)(m0 + r) * HID + colbase + nf*16] = v;
                }
            }
        }
    }
}

// ---------------- gather-reduce: out[t] += sum_k y[spos[t,k]] ----------------
__global__ __launch_bounds__(256) void reduce_kernel(
    const u16* __restrict__ y, const int* __restrict__ spos, float* __restrict__ out)
{
    int t = blockIdx.x;
    int c = threadIdx.x * 4;
    float4 o = *reinterpret_cast<const float4*>(out + (size_t)t*HID + c);
    #pragma unroll
    for (int k = 0; k < TOPK; ++k) {
        int p = spos[t*TOPK + k];
        u16x4 v = *reinterpret_cast<const u16x4*>(y + (size_t)p*HID + c);
        o.x += b2f(v[0]); o.y += b2f(v[1]); o.z += b2f(v[2]); o.w += b2f(v[3]);
    }
    *reinterpret_cast<float4*>(out + (size_t)t*HID + c) = o;
}

extern "C" void kernel_launch(void* const* d_in, const int* in_sizes, int n_in,
                              void* d_out, int out_size, void* d_ws, size_t ws_size,
                              hipStream_t stream)
{
    const float* x   = (const float*)d_in[0];
    const float* gw  = (const float*)d_in[1];
    const float* w1  = (const float*)d_in[2];
    const float* w2  = (const float*)d_in[3];
    const float* sgu = (const float*)d_in[4];
    const float* sdn = (const float*)d_in[5];
    float* out = (float*)d_out;

    char* p = (char*)d_ws;
    auto carve = [&](size_t bytes) { char* r = p; p += (bytes + 255) & ~(size_t)255; return r; };
    u16*   xb      = (u16*)  carve((size_t)M_TOK * HID * 2);
    u16*   h       = (u16*)  carve((size_t)TOTSLOT * 1024 * 2);
    u16*   hs      = (u16*)  carve((size_t)M_TOK * 2048 * 2);
    u16*   y       = (u16*)  carve((size_t)TOTSLOT * HID * 2);
    float* gwT     = (float*)carve((size_t)HID * NEXP * 4);
    int*   topk_id = (int*)  carve(M_TOK * TOPK * 4);
    float* topk_w  = (float*)carve(M_TOK * TOPK * 4);
    int*   counts  = (int*)  carve(NEXP * 4);
    int*   offs    = (int*)  carve((NEXP + 1) * 4);
    int*   cursor  = (int*)  carve(NEXP * 4);
    int*   stok    = (int*)  carve(TOTSLOT * 4);
    float* sw      = (float*)carve(TOTSLOT * 4);
    int*   spos    = (int*)  carve(TOTSLOT * 4);

    hipMemsetAsync(counts, 0, NEXP * 4, stream);
    convert_x_kernel<<<(M_TOK*HID/4 + 255)/256, 256, 0, stream>>>(x, xb);
    transpose_gw_kernel<<<(NEXP*HID + 255)/256, 256, 0, stream>>>(gw, gwT);
    router_kernel<<<M_TOK, 64, 0, stream>>>(x, gwT, topk_id, topk_w, counts);
    scan_kernel<<<1, 64, 0, stream>>>(counts, offs, cursor);
    fill_kernel<<<(TOTSLOT + 255)/256, 256, 0, stream>>>(topk_id, topk_w, cursor, stok, sw, spos);

    // shared expert path (writes d_out fully), routed experts into y, then gather
    gemm_kernel<1><<<dim3(32,8,1), 512, 0, stream>>>(xb, sgu, hs, nullptr, nullptr, nullptr, nullptr);
    gemm_kernel<3><<<dim3(16,16,1), 256, 0, stream>>>(hs, sdn, nullptr, out, nullptr, nullptr, nullptr);
    gemm_kernel<0><<<dim3(16,2,64), 512, 0, stream>>>(xb, w1, h, nullptr, offs, stok, sw);
    gemm_kernel<2><<<dim3(8,2,64),  512, 0, stream>>>(h, w2, y, nullptr, offs, stok, sw);
    reduce_kernel<<<M_TOK, 256, 0, stream>>>(y, spos, out);
}

// Round 7
// 622.340 us; speedup vs baseline: 2.6826x; 2.6826x over previous
//
#include <hip/hip_runtime.h>
#include <stdint.h>

#define M_TOK 2048
#define HID   1024
#define NEXP  64
#define TOPK  6
#define TOTSLOT (M_TOK*TOPK)   // 12288

typedef unsigned short u16;
typedef __attribute__((ext_vector_type(4))) u16   u16x4;
typedef __attribute__((ext_vector_type(8))) u16   u16x8;
typedef __attribute__((ext_vector_type(4))) float f32x4;
typedef __attribute__((ext_vector_type(8))) short bf16x8;

__device__ __forceinline__ u16 f2b(float f) {
    union { float f; uint32_t u; } v; v.f = f;
    uint32_t r = v.u + 0x7FFFu + ((v.u >> 16) & 1u);
    return (u16)(r >> 16);
}
__device__ __forceinline__ float b2f(u16 b) {
    union { uint32_t u; float f; } v; v.u = ((uint32_t)b) << 16; return v.f;
}

// ---------------- x fp32 -> bf16 ----------------
__global__ __launch_bounds__(256) void convert_x_kernel(const float* __restrict__ x,
                                                        u16* __restrict__ xb) {
    int i = (blockIdx.x * 256 + threadIdx.x) * 4;
    float4 v = *reinterpret_cast<const float4*>(x + i);
    u16x4 o; o[0] = f2b(v.x); o[1] = f2b(v.y); o[2] = f2b(v.z); o[3] = f2b(v.w);
    *reinterpret_cast<u16x4*>(xb + i) = o;
}

// ---------------- gw transpose: gwT[k][e] so router lanes read coalesced ----------------
__global__ __launch_bounds__(256) void transpose_gw_kernel(const float* __restrict__ gw,
                                                           float* __restrict__ gwT) {
    int i = blockIdx.x * 256 + threadIdx.x;   // 65536 elements
    int e = i >> 10, k = i & 1023;
    gwT[k * NEXP + e] = gw[i];
}

// ---------------- router: fp64 logits (coalesced gwT), grouped topk ----------------
__global__ __launch_bounds__(64) void router_kernel(
    const float* __restrict__ x, const float* __restrict__ gwT,
    int* __restrict__ topk_id, float* __restrict__ topk_w, int* __restrict__ counts)
{
    int t = blockIdx.x, lane = threadIdx.x;
    __shared__ float xr[HID];
    for (int k = lane; k < HID; k += 64) xr[k] = x[(size_t)t * HID + k];
    __syncthreads();
    double s0 = 0.0, s1 = 0.0, s2 = 0.0, s3 = 0.0;
    for (int k = 0; k < HID; k += 4) {
        s0 += (double)xr[k]   * (double)gwT[(k)   * NEXP + lane];
        s1 += (double)xr[k+1] * (double)gwT[(k+1) * NEXP + lane];
        s2 += (double)xr[k+2] * (double)gwT[(k+2) * NEXP + lane];
        s3 += (double)xr[k+3] * (double)gwT[(k+3) * NEXP + lane];
    }
    double s = (s0 + s1) + (s2 + s3);
    __shared__ double lg[NEXP];
    __shared__ float  pr[NEXP];
    float sf = (float)s;
    float mx = sf;
    for (int o = 32; o; o >>= 1) mx = fmaxf(mx, __shfl_xor(mx, o));
    float ev = __expf(sf - mx);
    float sum = ev;
    for (int o = 32; o; o >>= 1) sum += __shfl_xor(sum, o);
    lg[lane] = s; pr[lane] = ev / sum;
    __syncthreads();
    if (lane == 0) {
        double gs[8];
        #pragma unroll
        for (int g = 0; g < 8; ++g) {
            double m = lg[g*8];
            #pragma unroll
            for (int i = 1; i < 8; ++i) m = fmax(m, lg[g*8+i]);
            gs[g] = m;
        }
        unsigned gsel = 0;
        for (int r = 0; r < 3; ++r) {
            int bi = 0; double bv = -1e300;
            for (int g = 0; g < 8; ++g)
                if (!((gsel>>g)&1u) && gs[g] > bv) { bv = gs[g]; bi = g; }
            gsel |= 1u << bi;
        }
        unsigned long long taken = 0;
        for (int r = 0; r < TOPK; ++r) {
            int bi = 0; double bv = -1e300;
            for (int e = 0; e < NEXP; ++e) {
                if (!((gsel >> (e>>3)) & 1u)) continue;
                if ((taken >> e) & 1ull) continue;
                if (lg[e] > bv) { bv = lg[e]; bi = e; }
            }
            taken |= 1ull << bi;
            topk_id[t*TOPK + r] = bi;
            topk_w[t*TOPK + r] = pr[bi];
            atomicAdd(&counts[bi], 1);
        }
    }
}

__global__ void scan_kernel(const int* __restrict__ counts, int* __restrict__ offs,
                            int* __restrict__ cursor) {
    if (threadIdx.x == 0) {
        int acc = 0;
        for (int e = 0; e < NEXP; ++e) { offs[e] = acc; cursor[e] = acc; acc += counts[e]; }
        offs[NEXP] = acc;
    }
}

__global__ __launch_bounds__(256) void fill_kernel(
    const int* __restrict__ topk_id, const float* __restrict__ topk_w,
    int* __restrict__ cursor, int* __restrict__ stok, float* __restrict__ sw,
    int* __restrict__ spos)
{
    int idx = blockIdx.x*256 + threadIdx.x;
    if (idx >= TOTSLOT) return;
    int e = topk_id[idx];
    int pos = atomicAdd(&cursor[e], 1);
    stok[pos] = idx / TOPK;
    sw[pos] = topk_w[idx];
    spos[idx] = pos;
}

// ---------------- unified MFMA GEMM: BM=256, BK=32, 512 thr, 2 blocks/CU ----------------
// KIND 0: routed gate/up  BN=128  A=x_bf16[tok] K=1024, B=w1[e] -> h (silu*up*w, bf16)
// KIND 1: shared gate/up  BN=128  A=x_bf16     K=1024, B=sgu  -> hs (bf16)
// KIND 2: routed down     BN=128  A=h          K=1024, B=w2[e]-> y  (bf16)
// KIND 3: shared down     BN=64   A=hs         K=2048, B=sdn  -> Out (f32)
// 8 waves x (32 M-rows x BN). LDS ~50KB -> 2 independent blocks/CU (decoupled barriers).
template<int KIND>
__global__ __launch_bounds__(512, 4) void gemm_kernel(
    const u16* __restrict__ A, const float* __restrict__ Bw,
    u16* __restrict__ Hout, float* __restrict__ Out,
    const int* __restrict__ offs, const int* __restrict__ stok,
    const float* __restrict__ sw)
{
    constexpr bool G1     = (KIND == 0 || KIND == 1);
    constexpr bool ROUTED = (KIND == 0 || KIND == 2);
    constexpr int  BM     = 256;
    constexpr int  BN     = (KIND == 3) ? 64 : 128;
    constexpr int  NF     = BN / 16;
    constexpr int  KD     = (KIND == 3) ? 2048 : 1024;
    constexpr int  KITER  = KD / 32;
    constexpr int  NPAIR  = (KIND == 0) ? 1024 : 2048;  // up-row offset / Hout stride
    constexpr int  TPR    = 512 / BN;     // B-stage threads per row (4 or 8)
    constexpr int  CPT    = 32 / TPR;     // B fp32 cols per thread (8 or 4)
    constexpr int  BREG   = CPT / 4;      // float4 per thread (2 or 1)

    __shared__ u16 As[2][BM*32];          // 32 KB
    __shared__ u16 Bs[2][BN*32];          // 16 KB (8 KB kind 3)
    __shared__ int   tkl[ROUTED ? BM : 1];
    __shared__ float swl[(KIND == 0) ? BM : 1];

    const int tid  = threadIdx.x;
    const int lane = tid & 63;
    const int wv   = tid >> 6;            // 8 waves, each owns 32 M-rows x BN

    const int e = ROUTED ? blockIdx.z : 0;
    int off = 0, cnt = M_TOK;
    if (ROUTED) { off = offs[e]; cnt = offs[e+1] - off; }
    const int m0 = blockIdx.y * BM;
    if (m0 >= cnt) return;
    const int nblk = blockIdx.x;

    if (ROUTED && tid < BM) {
        int gr = m0 + tid;
        if (KIND == 0) {
            tkl[tid] = (gr < cnt) ? stok[off + gr] : 0;
            swl[tid] = (gr < cnt) ? sw[off + gr] : 0.f;
        } else {
            int r = off + gr; if (r > TOTSLOT-1) r = TOTSLOT-1;
            tkl[tid] = r;
        }
    }
    __syncthreads();

    // A staging: wave stages its own 32 rows (2 calls x 16 rows). Linear LDS dest
    // (dest byte = base + 16*lane), XOR-swizzled K-chunks via pre-swizzled global source.
    const int acol8 = (lane & 3) ^ ((lane >> 3) & 3);   // pre-swizzled source chunk
    int aoff[2];
    #pragma unroll
    for (int j = 0; j < 2; ++j) {
        int r = wv*32 + j*16 + (lane >> 2);
        int arow = ROUTED ? tkl[r] : (m0 + r);
        aoff[j] = arow * KD + acol8 * 8;
    }

    const float* Be = Bw;
    if (KIND == 0) Be += (size_t)e * (size_t)(2*1024*1024);
    if (KIND == 2) Be += (size_t)e * (size_t)(1024*1024);
    const int rb = tid / TPR;             // B tile row 0..BN-1
    const int q  = tid % TPR;
    int brow;
    if (G1) brow = (rb < 64) ? (nblk*64 + rb) : (NPAIR + nblk*64 + (rb - 64));
    else    brow = nblk*BN + rb;
    const float* bsrc = Be + (size_t)brow * KD + q*CPT;

    float4 br[BREG];

    auto stageA = [&](int buf, int k0) {
        #pragma unroll
        for (int j = 0; j < 2; ++j) {
            __builtin_amdgcn_global_load_lds(
                (const __attribute__((address_space(1))) uint32_t*)(A + (size_t)(aoff[j] + k0)),
                (__attribute__((address_space(3))) uint32_t*)(&As[buf][(wv*32 + j*16)*32]),
                16, 0, 0);
        }
    };
    auto loadB = [&](int k0) {
        #pragma unroll
        for (int j = 0; j < BREG; ++j)
            br[j] = *reinterpret_cast<const float4*>(bsrc + k0 + j*4);
    };
    auto storeB = [&](int buf) {
        char* bd = (char*)&Bs[buf][0] + rb*64;
        if constexpr (CPT == 8) {
            u16x8 w;
            w[0] = f2b(br[0].x); w[1] = f2b(br[0].y); w[2] = f2b(br[0].z); w[3] = f2b(br[0].w);
            w[4] = f2b(br[1].x); w[5] = f2b(br[1].y); w[6] = f2b(br[1].z); w[7] = f2b(br[1].w);
            *reinterpret_cast<u16x8*>(bd + ((q ^ ((rb >> 1) & 3)) << 4)) = w;
        } else {
            u16x4 w;
            w[0] = f2b(br[0].x); w[1] = f2b(br[0].y); w[2] = f2b(br[0].z); w[3] = f2b(br[0].w);
            *reinterpret_cast<u16x4*>(bd + (((q>>1) ^ ((rb >> 1) & 3)) << 4) + (q & 1) * 8) = w;
        }
    };

    f32x4 acc[2][NF];
    #pragma unroll
    for (int mf = 0; mf < 2; ++mf)
        #pragma unroll
        for (int nf = 0; nf < NF; ++nf)
            acc[mf][nf] = (f32x4){0.f, 0.f, 0.f, 0.f};

    const int slot = lane >> 4;
    const int xoff = ((slot ^ (((lane & 15) >> 1) & 3)) << 4);  // same for A and B reads

    auto mfma_phase = [&](int buf) {
        bf16x8 af[2];
        #pragma unroll
        for (int mf = 0; mf < 2; ++mf) {
            int row = wv*32 + mf*16 + (lane & 15);
            af[mf] = *reinterpret_cast<const bf16x8*>((const char*)&As[buf][0] + row*64 + xoff);
        }
        #pragma unroll
        for (int nf = 0; nf < NF; ++nf) {
            int rowb = nf*16 + (lane & 15);
            bf16x8 bfr = *reinterpret_cast<const bf16x8*>((const char*)&Bs[buf][0] + rowb*64 + xoff);
            #pragma unroll
            for (int mf = 0; mf < 2; ++mf)
                acc[mf][nf] = __builtin_amdgcn_mfma_f32_16x16x32_bf16(af[mf], bfr, acc[mf][nf], 0, 0, 0);
        }
    };

    // prologue: tile 0 resident
    stageA(0, 0);
    loadB(0);
    storeB(0);
    __syncthreads();

    for (int kt = 0; kt < KITER; ++kt) {
        const int cur = kt & 1, nxt = cur ^ 1;
        const bool more = (kt + 1 < KITER);
        if (more) { stageA(nxt, (kt + 1) * 32); loadB((kt + 1) * 32); }
        mfma_phase(cur);
        if (more) storeB(nxt);
        __syncthreads();
    }

    if constexpr (G1) {
        const int colbase = nblk*64 + (lane & 15);
        #pragma unroll
        for (int mf = 0; mf < 2; ++mf) {
            #pragma unroll
            for (int j = 0; j < 4; ++j) {
                int r = wv*32 + mf*16 + (lane >> 4)*4 + j;
                if (ROUTED && (m0 + r) >= cnt) continue;
                float wgt = (KIND == 0) ? swl[r] : 1.0f;
                size_t orow = (size_t)(ROUTED ? (off + m0 + r) : (m0 + r));
                #pragma unroll
                for (int nf = 0; nf < 4; ++nf) {
                    float g = acc[mf][nf][j];
                    float u = acc[mf][nf+4][j];
                    float hv = (g / (1.f + __expf(-g))) * u * wgt;
                    Hout[orow * NPAIR + colbase + nf*16] = f2b(hv);
                }
            }
        }
    } else {
        const int colbase = nblk*BN + (lane & 15);
        #pragma unroll
        for (int mf = 0; mf < 2; ++mf) {
            #pragma unroll
            for (int j = 0; j < 4; ++j) {
                int r = wv*32 + mf*16 + (lane >> 4)*4 + j;
                if (ROUTED && (m0 + r) >= cnt) continue;
                #pragma unroll
                for (int nf = 0; nf < NF; ++nf) {
                    float v = acc[mf][nf][j];
                    if (KIND == 2) Hout[(size_t)(off + m0 + r) * HID + colbase + nf*16] = f2b(v);
                    else           Out[(size_t)(m0 + r) * HID + colbase + nf*16] = v;
                }
            }
        }
    }
}

// ---------------- gather-reduce: out[t] += sum_k y[spos[t,k]] ----------------
__global__ __launch_bounds__(256) void reduce_kernel(
    const u16* __restrict__ y, const int* __restrict__ spos, float* __restrict__ out)
{
    int t = blockIdx.x;
    int c = threadIdx.x * 4;
    float4 o = *reinterpret_cast<const float4*>(out + (size_t)t*HID + c);
    #pragma unroll
    for (int k = 0; k < TOPK; ++k) {
        int p = spos[t*TOPK + k];
        u16x4 v = *reinterpret_cast<const u16x4*>(y + (size_t)p*HID + c);
        o.x += b2f(v[0]); o.y += b2f(v[1]); o.z += b2f(v[2]); o.w += b2f(v[3]);
    }
    *reinterpret_cast<float4*>(out + (size_t)t*HID + c) = o;
}

extern "C" void kernel_launch(void* const* d_in, const int* in_sizes, int n_in,
                              void* d_out, int out_size, void* d_ws, size_t ws_size,
                              hipStream_t stream)
{
    const float* x   = (const float*)d_in[0];
    const float* gw  = (const float*)d_in[1];
    const float* w1  = (const float*)d_in[2];
    const float* w2  = (const float*)d_in[3];
    const float* sgu = (const float*)d_in[4];
    const float* sdn = (const float*)d_in[5];
    float* out = (float*)d_out;

    char* p = (char*)d_ws;
    auto carve = [&](size_t bytes) { char* r = p; p += (bytes + 255) & ~(size_t)255; return r; };
    u16*   xb      = (u16*)  carve((size_t)M_TOK * HID * 2);
    u16*   h       = (u16*)  carve((size_t)TOTSLOT * 1024 * 2);
    u16*   hs      = (u16*)  carve((size_t)M_TOK * 2048 * 2);
    u16*   y       = (u16*)  carve((size_t)TOTSLOT * HID * 2);
    float* gwT     = (float*)carve((size_t)HID * NEXP * 4);
    int*   topk_id = (int*)  carve(M_TOK * TOPK * 4);
    float* topk_w  = (float*)carve(M_TOK * TOPK * 4);
    int*   counts  = (int*)  carve(NEXP * 4);
    int*   offs    = (int*)  carve((NEXP + 1) * 4);
    int*   cursor  = (int*)  carve(NEXP * 4);
    int*   stok    = (int*)  carve(TOTSLOT * 4);
    float* sw      = (float*)carve(TOTSLOT * 4);
    int*   spos    = (int*)  carve(TOTSLOT * 4);

    hipMemsetAsync(counts, 0, NEXP * 4, stream);
    convert_x_kernel<<<(M_TOK*HID/4 + 255)/256, 256, 0, stream>>>(x, xb);
    transpose_gw_kernel<<<(NEXP*HID + 255)/256, 256, 0, stream>>>(gw, gwT);
    router_kernel<<<M_TOK, 64, 0, stream>>>(x, gwT, topk_id, topk_w, counts);
    scan_kernel<<<1, 64, 0, stream>>>(counts, offs, cursor);
    fill_kernel<<<(TOTSLOT + 255)/256, 256, 0, stream>>>(topk_id, topk_w, cursor, stok, sw, spos);

    // shared expert path (writes d_out fully), routed experts into y, then gather
    gemm_kernel<1><<<dim3(32,8,1),  512, 0, stream>>>(xb, sgu, hs, nullptr, nullptr, nullptr, nullptr);
    gemm_kernel<3><<<dim3(16,8,1),  512, 0, stream>>>(hs, sdn, nullptr, out, nullptr, nullptr, nullptr);
    gemm_kernel<0><<<dim3(16,2,64), 512, 0, stream>>>(xb, w1, h, nullptr, offs, stok, sw);
    gemm_kernel<2><<<dim3(8,2,64),  512, 0, stream>>>(h, w2, y, nullptr, offs, stok, sw);
    reduce_kernel<<<M_TOK, 256, 0, stream>>>(y, spos, out);
}